// Round 16
// baseline (51.524 us; speedup 1.0000x reference)
//
#include <hip/hip_runtime.h>
#include <math.h>

#define T_LEN 24000
#define NCH   64
#define NSEQ  16       // BATCH * 2 directions
#define LCH   192      // chunk length (3 x 64)
#define KCH   125      // KCH*LCH == T_LEN
#define NBLK  (NSEQ * KCH)
#define WT    32       // output w-tile width (r10-proven)
#define KB2   25       // P2 register batch (KCH % KB2 == 0)
#define NXCD  8

static_assert(KCH * LCH == T_LEN, "chunking must cover T");
static_assert(KCH % KB2 == 0, "P2 batches must cover KCH");
static_assert(NBLK % NXCD == 0, "bijective XCD swizzle needs nwg % 8 == 0");

// XCD-aware swizzle: consecutive logical blocks land on the same XCD.
__device__ __forceinline__ int swz(int b) {
    return (b % NXCD) * (NBLK / NXCD) + b / NXCD;
}

// Host-computed constants, passed by value (kernarg): 7 x 64 x 8 = 3584 B.
struct Coeffs {
    double a1[NCH], a2[NCH], b0[NCH];
    double A00[NCH], A01[NCH], A10[NCH], A11[NCH];  // A = M^LCH (entry->end)
};

// ws layout: stEnd double2[ST_D2] ; stEntry double2[ST_D2]
#define ST_D2     ((size_t)NSEQ * NCH * KCH)               // 128000
#define WS_FULL   (2 * ST_D2 * sizeof(double2))            // 4,096,000 B
#define WS_MID    (ST_D2 * sizeof(double2))                // 2,048,000 B

// ---- kernel A: zero-entry chunk end states --------------------------------
__global__ __launch_bounds__(64) void iir_endstates(
        const float* __restrict__ x, const Coeffs cf,
        double2* __restrict__ stEnd) {
    __shared__ float xs[LCH];
    const int g = swz(blockIdx.x), k = g % KCH, s = g / KCH;
    const int bi = s >> 1, dir = s & 1, c = threadIdx.x;
    const double a1 = cf.a1[c], a2 = cf.a2[c], b0 = cf.b0[c];
    const float* xb = x + (size_t)bi * T_LEN;
    const int t0 = k * LCH;
    #pragma unroll
    for (int w = 0; w < LCH / 64; ++w) {
        const int t = t0 + w * 64 + c;
        xs[w * 64 + c] = (dir == 0) ? xb[t] : xb[T_LEN - 1 - t];
    }
    __syncthreads();
    double y1 = 0.0, y2 = 0.0;
    #pragma unroll 16
    for (int j = 0; j < LCH; ++j) {
        // y1->y critical path is a single fp64 fma (y2 known 2 steps early)
        double y = fma(-a1, y1, fma(-a2, y2, b0 * (double)xs[j]));
        y2 = y1; y1 = y;
    }
    stEnd[((size_t)s * KCH + k) * NCH + c] = make_double2(y1, y2);
}

// ---- kernel P2: per-sequence entry-state scan (16 blocks) -----------------
__global__ __launch_bounds__(64) void iir_entries(
        const Coeffs cf, const double2* __restrict__ stEnd,
        double2* __restrict__ stEntry) {
    const int s = blockIdx.x, c = threadIdx.x;
    const double A00 = cf.A00[c], A01 = cf.A01[c];
    const double A10 = cf.A10[c], A11 = cf.A11[c];
    const double2* __restrict__ src = stEnd + (size_t)s * KCH * NCH;
    double2* __restrict__ dst = stEntry + (size_t)s * KCH * NCH;
    double in1 = 0.0, in2 = 0.0;
    for (int kb = 0; kb < KCH; kb += KB2) {
        double2 e[KB2];
        #pragma unroll
        for (int j = 0; j < KB2; ++j)
            e[j] = src[(size_t)(kb + j) * NCH + c];   // static idx -> VGPRs
        #pragma unroll
        for (int j = 0; j < KB2; ++j) {
            dst[(size_t)(kb + j) * NCH + c] = make_double2(in1, in2);
            const double n1 = e[j].x + fma(A00, in1, A01 * in2);
            const double n2 = e[j].y + fma(A10, in1, A11 * in2);
            in1 = n1; in2 = n2;
        }
    }
}

// ---- kernel B: chunk re-run from entry state + float4 output --------------
// tile stride 36 floats: 144 B rows (16B-aligned), 36 mod 32 == 4 -> both
// b128 sides bank-balanced. LDS < 10 KB.
__global__ __launch_bounds__(64) void iir_output(
        const float* __restrict__ x, const Coeffs cf,
        const double2* __restrict__ stEntry, float* __restrict__ out) {
    __shared__ float xs[LCH];
    __shared__ __align__(16) float tile[NCH][36];
    const int g = swz(blockIdx.x), k = g % KCH, s = g / KCH;
    const int bi = s >> 1, dir = s & 1, c = threadIdx.x;
    const double a1 = cf.a1[c], a2 = cf.a2[c], b0 = cf.b0[c];
    const double2 ent = stEntry[((size_t)s * KCH + k) * NCH + c];
    const float* xb = x + (size_t)bi * T_LEN;
    const int t0 = k * LCH;
    #pragma unroll
    for (int w = 0; w < LCH / 64; ++w) {
        const int t = t0 + w * 64 + c;
        xs[w * 64 + c] = (dir == 0) ? xb[t] : xb[T_LEN - 1 - t];
    }
    __syncthreads();
    double y1 = ent.x, y2 = ent.y;
    const int rowoff = bi * 128 + (dir ? 64 : 0);
    const int lo = c & 7, hi = c >> 3;
    for (int w = 0; w < LCH / WT; ++w) {
        #pragma unroll
        for (int j4 = 0; j4 < WT / 4; ++j4) {
            float4 v;
            #pragma unroll
            for (int e = 0; e < 4; ++e) {
                double y = fma(-a1, y1,
                               fma(-a2, y2,
                                   b0 * (double)xs[w * WT + j4 * 4 + e]));
                y2 = y1; y1 = y;
                (&v.x)[dir == 0 ? e : 3 - e] = (float)y;
            }
            const int q = (dir == 0) ? j4 : (WT / 4 - 1) - j4;
            *(float4*)&tile[c][4 * q] = v;   // ds_write_b128, bank-balanced
        }
        __syncthreads();
        const int cb = (dir == 0) ? (t0 + w * WT)
                                  : (T_LEN - WT - t0 - w * WT);
        #pragma unroll
        for (int i = 0; i < 8; ++i) {
            const int r = 8 * i + hi;
            *(float4*)&out[(size_t)(rowoff + r) * T_LEN + cb + 4 * lo] =
                *(const float4*)&tile[r][4 * lo];   // ds_read_b128, balanced
        }
        __syncthreads();
    }
}

// ---- mid tier: 2-kernel path (in-block scan) ------------------------------
__global__ __launch_bounds__(64) void iir_output_scan(
        const float* __restrict__ x, const Coeffs cf,
        const double2* __restrict__ stEnd, float* __restrict__ out) {
    __shared__ float xs[LCH];
    __shared__ __align__(16) float tile[NCH][36];
    const int g = swz(blockIdx.x), k = g % KCH, s = g / KCH;
    const int bi = s >> 1, dir = s & 1, c = threadIdx.x;
    const double a1  = cf.a1[c],  a2  = cf.a2[c],  b0 = cf.b0[c];
    const double A00 = cf.A00[c], A01 = cf.A01[c];
    const double A10 = cf.A10[c], A11 = cf.A11[c];
    const float* xb = x + (size_t)bi * T_LEN;
    const int t0 = k * LCH;
    #pragma unroll
    for (int w = 0; w < LCH / 64; ++w) {
        const int t = t0 + w * 64 + c;
        xs[w * 64 + c] = (dir == 0) ? xb[t] : xb[T_LEN - 1 - t];
    }
    const double2* __restrict__ src = stEnd + (size_t)s * KCH * NCH;
    double in1 = 0.0, in2 = 0.0;
    #pragma unroll 8
    for (int j = 0; j < k; ++j) {
        const double2 e = src[(size_t)j * NCH + c];
        const double n1 = e.x + fma(A00, in1, A01 * in2);
        const double n2 = e.y + fma(A10, in1, A11 * in2);
        in1 = n1; in2 = n2;
    }
    __syncthreads();
    double y1 = in1, y2 = in2;
    const int rowoff = bi * 128 + (dir ? 64 : 0);
    const int lo = c & 7, hi = c >> 3;
    for (int w = 0; w < LCH / WT; ++w) {
        #pragma unroll
        for (int j4 = 0; j4 < WT / 4; ++j4) {
            float4 v;
            #pragma unroll
            for (int e = 0; e < 4; ++e) {
                double y = fma(-a1, y1,
                               fma(-a2, y2,
                                   b0 * (double)xs[w * WT + j4 * 4 + e]));
                y2 = y1; y1 = y;
                (&v.x)[dir == 0 ? e : 3 - e] = (float)y;
            }
            const int q = (dir == 0) ? j4 : (WT / 4 - 1) - j4;
            *(float4*)&tile[c][4 * q] = v;
        }
        __syncthreads();
        const int cb = (dir == 0) ? (t0 + w * WT)
                                  : (T_LEN - WT - t0 - w * WT);
        #pragma unroll
        for (int i = 0; i < 8; ++i) {
            const int r = 8 * i + hi;
            *(float4*)&out[(size_t)(rowoff + r) * T_LEN + cb + 4 * lo] =
                *(const float4*)&tile[r][4 * lo];
        }
        __syncthreads();
    }
}

// ---- last-resort tier (no ws) ---------------------------------------------
__global__ __launch_bounds__(64) void iir_direct(
        const float* __restrict__ x, const Coeffs cf,
        float* __restrict__ out) {
    __shared__ float tile[NCH][65];
    const int s = blockIdx.x, bi = s >> 1, dir = s & 1, c = threadIdx.x;
    const double a1 = cf.a1[c], a2 = cf.a2[c], b0 = cf.b0[c];
    const float* xb = x + (size_t)bi * T_LEN;
    double y1 = 0.0, y2 = 0.0;
    for (int t0 = 0; t0 < T_LEN; t0 += 64) {
        #pragma unroll 8
        for (int j = 0; j < 64; ++j) {
            const int t = t0 + j;
            double xv = (dir == 0) ? (double)xb[t] : (double)xb[T_LEN - 1 - t];
            double y = fma(-a1, y1, fma(-a2, y2, b0 * xv));
            y2 = y1; y1 = y;
            tile[c][j] = (float)y;
        }
        __syncthreads();
        if (dir == 0) {
            #pragma unroll
            for (int r = 0; r < NCH; ++r)
                out[((size_t)(bi * 128 + r)) * T_LEN + (t0 + c)] = tile[r][c];
        } else {
            #pragma unroll
            for (int r = 0; r < NCH; ++r)
                out[((size_t)(bi * 128 + 64 + r)) * T_LEN +
                    (T_LEN - 1 - (t0 + c))] = tile[r][c];
        }
        __syncthreads();
    }
}

// Host-side constant computation (deterministic; runs at capture/validate).
static void make_coeffs(Coeffs& cf) {
    const double l10 = log(10.0), l100 = log(100.0);
    for (int c = 0; c < NCH; ++c) {
        double lf = (c == 63) ? l100 : l10 + (double)c * ((l100 - l10) / 63.0);
        double f  = exp(lf);
        double r  = (c == 63) ? 0.99999
                              : 0.9999 + (double)c * ((0.99999 - 0.9999) / 63.0);
        double th = (2.0 * M_PI) * f / 24000.0;
        double a1 = (-2.0 * r) * cos(th), a2 = r * r, b0 = (1.0 - r) * 0.5;
        double pj1 = 1.0, pj2 = 0.0, pj3 = 0.0;   // p[-1]=1, p[-2]=0
        for (int j = 0; j < LCH; ++j) {
            double p = fma(-a1, pj1, -a2 * pj2);
            pj3 = pj2; pj2 = pj1; pj1 = p;
        }
        cf.a1[c] = a1;  cf.a2[c] = a2;  cf.b0[c] = b0;
        cf.A00[c] = pj1;  cf.A01[c] = -a2 * pj2;
        cf.A10[c] = pj2;  cf.A11[c] = -a2 * pj3;
    }
}

extern "C" void kernel_launch(void* const* d_in, const int* in_sizes, int n_in,
                              void* d_out, int out_size, void* d_ws, size_t ws_size,
                              hipStream_t stream) {
    const float* x = (const float*)d_in[0];
    float* out = (float*)d_out;

    Coeffs cf;
    make_coeffs(cf);

    if (d_ws != nullptr && ws_size >= WS_FULL) {
        double2* stEnd = (double2*)d_ws;
        double2* stEntry = stEnd + ST_D2;
        iir_endstates<<<NBLK, 64, 0, stream>>>(x, cf, stEnd);
        iir_entries<<<NSEQ, 64, 0, stream>>>(cf, stEnd, stEntry);
        // MEASUREMENT ROUND: launch B twice (idempotent — writes identical
        // values). dur delta vs r13's 34.7 µs == B's standalone duration.
        iir_output<<<NBLK, 64, 0, stream>>>(x, cf, stEntry, out);
        iir_output<<<NBLK, 64, 0, stream>>>(x, cf, stEntry, out);
    } else if (d_ws != nullptr && ws_size >= WS_MID) {
        double2* stEnd = (double2*)d_ws;
        iir_endstates<<<NBLK, 64, 0, stream>>>(x, cf, stEnd);
        iir_output_scan<<<NBLK, 64, 0, stream>>>(x, cf, stEnd, out);
    } else {
        iir_direct<<<NSEQ, 64, 0, stream>>>(x, cf, out);
    }
}

// Round 17
// 34.600 us; speedup vs baseline: 1.4891x; 1.4891x over previous
//
#include <hip/hip_runtime.h>
#include <math.h>

#define T_LEN 24000
#define NCH   64
#define NSEQ  16       // BATCH * 2 directions
#define LCH   192      // chunk length (3 x 64)
#define KCH   125      // KCH*LCH == T_LEN
#define NBLK  (NSEQ * KCH)
#define WT    32       // output w-tile width (r10-proven)
#define KB2   25       // P2 register batch (KCH % KB2 == 0)
#define NXCD  8

static_assert(KCH * LCH == T_LEN, "chunking must cover T");
static_assert(KCH % KB2 == 0, "P2 batches must cover KCH");
static_assert(NBLK % NXCD == 0, "bijective XCD swizzle needs nwg % 8 == 0");

// XCD-aware swizzle: consecutive logical blocks land on the same XCD.
__device__ __forceinline__ int swz(int b) {
    return (b % NXCD) * (NBLK / NXCD) + b / NXCD;
}

// Host-computed constants, passed by value (kernarg): 7 x 64 x 8 = 3584 B.
struct Coeffs {
    double a1[NCH], a2[NCH], b0[NCH];
    double A00[NCH], A01[NCH], A10[NCH], A11[NCH];  // A = M^LCH (entry->end)
};

// ws layout: stEnd double2[ST_D2] ; stEntry double2[ST_D2]
#define ST_D2     ((size_t)NSEQ * NCH * KCH)               // 128000
#define WS_FULL   (2 * ST_D2 * sizeof(double2))            // 4,096,000 B
#define WS_MID    (ST_D2 * sizeof(double2))                // 2,048,000 B

// ---- kernel A: zero-entry chunk end states --------------------------------
__global__ __launch_bounds__(64) void iir_endstates(
        const float* __restrict__ x, const Coeffs cf,
        double2* __restrict__ stEnd) {
    __shared__ float xs[LCH];
    const int g = swz(blockIdx.x), k = g % KCH, s = g / KCH;
    const int bi = s >> 1, dir = s & 1, c = threadIdx.x;
    const double a1 = cf.a1[c], a2 = cf.a2[c], b0 = cf.b0[c];
    const float* xb = x + (size_t)bi * T_LEN;
    const int t0 = k * LCH;
    #pragma unroll
    for (int w = 0; w < LCH / 64; ++w) {
        const int t = t0 + w * 64 + c;
        xs[w * 64 + c] = (dir == 0) ? xb[t] : xb[T_LEN - 1 - t];
    }
    __syncthreads();
    double y1 = 0.0, y2 = 0.0;
    #pragma unroll 16
    for (int j = 0; j < LCH; ++j) {
        // y1->y critical path is a single fp64 fma (y2 known 2 steps early)
        double y = fma(-a1, y1, fma(-a2, y2, b0 * (double)xs[j]));
        y2 = y1; y1 = y;
    }
    stEnd[((size_t)s * KCH + k) * NCH + c] = make_double2(y1, y2);
}

// ---- kernel P2: per-sequence entry-state scan (16 blocks) -----------------
__global__ __launch_bounds__(64) void iir_entries(
        const Coeffs cf, const double2* __restrict__ stEnd,
        double2* __restrict__ stEntry) {
    const int s = blockIdx.x, c = threadIdx.x;
    const double A00 = cf.A00[c], A01 = cf.A01[c];
    const double A10 = cf.A10[c], A11 = cf.A11[c];
    const double2* __restrict__ src = stEnd + (size_t)s * KCH * NCH;
    double2* __restrict__ dst = stEntry + (size_t)s * KCH * NCH;
    double in1 = 0.0, in2 = 0.0;
    for (int kb = 0; kb < KCH; kb += KB2) {
        double2 e[KB2];
        #pragma unroll
        for (int j = 0; j < KB2; ++j)
            e[j] = src[(size_t)(kb + j) * NCH + c];   // static idx -> VGPRs
        #pragma unroll
        for (int j = 0; j < KB2; ++j) {
            dst[(size_t)(kb + j) * NCH + c] = make_double2(in1, in2);
            const double n1 = e[j].x + fma(A00, in1, A01 * in2);
            const double n2 = e[j].y + fma(A10, in1, A11 * in2);
            in1 = n1; in2 = n2;
        }
    }
}

// ---- kernel B: chunk re-run from entry state + float4 output --------------
// Measured (r16 double-launch): ~16.8 us standalone = 6.0-6.5 TB/s effective
// -> at the achievable write-BW roofline (fill kernels: 6.3-6.8 TB/s).
// tile stride 36 floats: 144 B rows (16B-aligned), 36 mod 32 == 4 -> both
// b128 sides bank-balanced. LDS < 10 KB.
__global__ __launch_bounds__(64) void iir_output(
        const float* __restrict__ x, const Coeffs cf,
        const double2* __restrict__ stEntry, float* __restrict__ out) {
    __shared__ float xs[LCH];
    __shared__ __align__(16) float tile[NCH][36];
    const int g = swz(blockIdx.x), k = g % KCH, s = g / KCH;
    const int bi = s >> 1, dir = s & 1, c = threadIdx.x;
    const double a1 = cf.a1[c], a2 = cf.a2[c], b0 = cf.b0[c];
    const double2 ent = stEntry[((size_t)s * KCH + k) * NCH + c];
    const float* xb = x + (size_t)bi * T_LEN;
    const int t0 = k * LCH;
    #pragma unroll
    for (int w = 0; w < LCH / 64; ++w) {
        const int t = t0 + w * 64 + c;
        xs[w * 64 + c] = (dir == 0) ? xb[t] : xb[T_LEN - 1 - t];
    }
    __syncthreads();
    double y1 = ent.x, y2 = ent.y;
    const int rowoff = bi * 128 + (dir ? 64 : 0);
    const int lo = c & 7, hi = c >> 3;
    for (int w = 0; w < LCH / WT; ++w) {
        #pragma unroll
        for (int j4 = 0; j4 < WT / 4; ++j4) {
            float4 v;
            #pragma unroll
            for (int e = 0; e < 4; ++e) {
                double y = fma(-a1, y1,
                               fma(-a2, y2,
                                   b0 * (double)xs[w * WT + j4 * 4 + e]));
                y2 = y1; y1 = y;
                (&v.x)[dir == 0 ? e : 3 - e] = (float)y;
            }
            const int q = (dir == 0) ? j4 : (WT / 4 - 1) - j4;
            *(float4*)&tile[c][4 * q] = v;   // ds_write_b128, bank-balanced
        }
        __syncthreads();
        const int cb = (dir == 0) ? (t0 + w * WT)
                                  : (T_LEN - WT - t0 - w * WT);
        #pragma unroll
        for (int i = 0; i < 8; ++i) {
            const int r = 8 * i + hi;
            *(float4*)&out[(size_t)(rowoff + r) * T_LEN + cb + 4 * lo] =
                *(const float4*)&tile[r][4 * lo];   // ds_read_b128, balanced
        }
        __syncthreads();
    }
}

// ---- mid tier: 2-kernel path (in-block scan) ------------------------------
__global__ __launch_bounds__(64) void iir_output_scan(
        const float* __restrict__ x, const Coeffs cf,
        const double2* __restrict__ stEnd, float* __restrict__ out) {
    __shared__ float xs[LCH];
    __shared__ __align__(16) float tile[NCH][36];
    const int g = swz(blockIdx.x), k = g % KCH, s = g / KCH;
    const int bi = s >> 1, dir = s & 1, c = threadIdx.x;
    const double a1  = cf.a1[c],  a2  = cf.a2[c],  b0 = cf.b0[c];
    const double A00 = cf.A00[c], A01 = cf.A01[c];
    const double A10 = cf.A10[c], A11 = cf.A11[c];
    const float* xb = x + (size_t)bi * T_LEN;
    const int t0 = k * LCH;
    #pragma unroll
    for (int w = 0; w < LCH / 64; ++w) {
        const int t = t0 + w * 64 + c;
        xs[w * 64 + c] = (dir == 0) ? xb[t] : xb[T_LEN - 1 - t];
    }
    const double2* __restrict__ src = stEnd + (size_t)s * KCH * NCH;
    double in1 = 0.0, in2 = 0.0;
    #pragma unroll 8
    for (int j = 0; j < k; ++j) {
        const double2 e = src[(size_t)j * NCH + c];
        const double n1 = e.x + fma(A00, in1, A01 * in2);
        const double n2 = e.y + fma(A10, in1, A11 * in2);
        in1 = n1; in2 = n2;
    }
    __syncthreads();
    double y1 = in1, y2 = in2;
    const int rowoff = bi * 128 + (dir ? 64 : 0);
    const int lo = c & 7, hi = c >> 3;
    for (int w = 0; w < LCH / WT; ++w) {
        #pragma unroll
        for (int j4 = 0; j4 < WT / 4; ++j4) {
            float4 v;
            #pragma unroll
            for (int e = 0; e < 4; ++e) {
                double y = fma(-a1, y1,
                               fma(-a2, y2,
                                   b0 * (double)xs[w * WT + j4 * 4 + e]));
                y2 = y1; y1 = y;
                (&v.x)[dir == 0 ? e : 3 - e] = (float)y;
            }
            const int q = (dir == 0) ? j4 : (WT / 4 - 1) - j4;
            *(float4*)&tile[c][4 * q] = v;
        }
        __syncthreads();
        const int cb = (dir == 0) ? (t0 + w * WT)
                                  : (T_LEN - WT - t0 - w * WT);
        #pragma unroll
        for (int i = 0; i < 8; ++i) {
            const int r = 8 * i + hi;
            *(float4*)&out[(size_t)(rowoff + r) * T_LEN + cb + 4 * lo] =
                *(const float4*)&tile[r][4 * lo];
        }
        __syncthreads();
    }
}

// ---- last-resort tier (no ws) ---------------------------------------------
__global__ __launch_bounds__(64) void iir_direct(
        const float* __restrict__ x, const Coeffs cf,
        float* __restrict__ out) {
    __shared__ float tile[NCH][65];
    const int s = blockIdx.x, bi = s >> 1, dir = s & 1, c = threadIdx.x;
    const double a1 = cf.a1[c], a2 = cf.a2[c], b0 = cf.b0[c];
    const float* xb = x + (size_t)bi * T_LEN;
    double y1 = 0.0, y2 = 0.0;
    for (int t0 = 0; t0 < T_LEN; t0 += 64) {
        #pragma unroll 8
        for (int j = 0; j < 64; ++j) {
            const int t = t0 + j;
            double xv = (dir == 0) ? (double)xb[t] : (double)xb[T_LEN - 1 - t];
            double y = fma(-a1, y1, fma(-a2, y2, b0 * xv));
            y2 = y1; y1 = y;
            tile[c][j] = (float)y;
        }
        __syncthreads();
        if (dir == 0) {
            #pragma unroll
            for (int r = 0; r < NCH; ++r)
                out[((size_t)(bi * 128 + r)) * T_LEN + (t0 + c)] = tile[r][c];
        } else {
            #pragma unroll
            for (int r = 0; r < NCH; ++r)
                out[((size_t)(bi * 128 + 64 + r)) * T_LEN +
                    (T_LEN - 1 - (t0 + c))] = tile[r][c];
        }
        __syncthreads();
    }
}

// Host-side constant computation (deterministic; runs at capture/validate).
static void make_coeffs(Coeffs& cf) {
    const double l10 = log(10.0), l100 = log(100.0);
    for (int c = 0; c < NCH; ++c) {
        double lf = (c == 63) ? l100 : l10 + (double)c * ((l100 - l10) / 63.0);
        double f  = exp(lf);
        double r  = (c == 63) ? 0.99999
                              : 0.9999 + (double)c * ((0.99999 - 0.9999) / 63.0);
        double th = (2.0 * M_PI) * f / 24000.0;
        double a1 = (-2.0 * r) * cos(th), a2 = r * r, b0 = (1.0 - r) * 0.5;
        double pj1 = 1.0, pj2 = 0.0, pj3 = 0.0;   // p[-1]=1, p[-2]=0
        for (int j = 0; j < LCH; ++j) {
            double p = fma(-a1, pj1, -a2 * pj2);
            pj3 = pj2; pj2 = pj1; pj1 = p;
        }
        cf.a1[c] = a1;  cf.a2[c] = a2;  cf.b0[c] = b0;
        cf.A00[c] = pj1;  cf.A01[c] = -a2 * pj2;
        cf.A10[c] = pj2;  cf.A11[c] = -a2 * pj3;
    }
}

extern "C" void kernel_launch(void* const* d_in, const int* in_sizes, int n_in,
                              void* d_out, int out_size, void* d_ws, size_t ws_size,
                              hipStream_t stream) {
    const float* x = (const float*)d_in[0];
    float* out = (float*)d_out;

    Coeffs cf;
    make_coeffs(cf);

    if (d_ws != nullptr && ws_size >= WS_FULL) {
        double2* stEnd = (double2*)d_ws;
        double2* stEntry = stEnd + ST_D2;
        iir_endstates<<<NBLK, 64, 0, stream>>>(x, cf, stEnd);
        iir_entries<<<NSEQ, 64, 0, stream>>>(cf, stEnd, stEntry);
        iir_output<<<NBLK, 64, 0, stream>>>(x, cf, stEntry, out);
    } else if (d_ws != nullptr && ws_size >= WS_MID) {
        double2* stEnd = (double2*)d_ws;
        iir_endstates<<<NBLK, 64, 0, stream>>>(x, cf, stEnd);
        iir_output_scan<<<NBLK, 64, 0, stream>>>(x, cf, stEnd, out);
    } else {
        iir_direct<<<NSEQ, 64, 0, stream>>>(x, cf, out);
    }
}